// Round 2
// baseline (4815.344 us; speedup 1.0000x reference)
//
#include <hip/hip_runtime.h>

// BTT fused kernel, round 1: correctness-first fp32 VALU version.
// out[b, y*64+i] = bias[y*64+i]
//                + sum_{x,a} ( sum_u X[b, x*64+u] * core0[(x*64+u)*256 + i*4+a] )
//                            * core1[((x*64+y)*64 + i)*4 + a]
//
// Grid: (256 batch tiles of TB=32 rows) x (8 i-tiles of TI=8).
// Per block: loop x-chunk 0..63; stage X chunk (32x64) in LDS; stage-1 writes
// z1 slice (32 x 32) to LDS; stage-2 accumulates out tile (32 x 64 x 8) in regs.
// blockIdx.x = batch tile (fastest) so the 8 i-tile blocks sharing an x-tile
// are 256 apart in linear order -> same XCD (mod-8) -> shared L2 for x re-reads.

#define TB 32
#define TI 8
#define NTHREADS 512

__global__ __launch_bounds__(NTHREADS, 2) void btt_fused(
    const float* __restrict__ x,      // (8192, 4096)
    const float* __restrict__ core0,  // (64,64,64,4,1) flat
    const float* __restrict__ core1,  // (64,64,64,1,4) flat
    const float* __restrict__ bias,   // (4096)
    float* __restrict__ out)          // (8192, 4096)
{
    __shared__ float Xc[TB][65];   // x chunk, +1 pad: broadcast reads conflict-free
    __shared__ float z1c[TB][36];  // z1 slice [b][(ii,a)], stride 36 to spread banks

    const int t  = threadIdx.x;
    const int bt = blockIdx.x;     // 0..255 batch tile
    const int it = blockIdx.y;     // 0..7 i tile
    const int b0 = bt * TB;
    const int i0 = it * TI;

    const int bb = t >> 4;         // 0..31: this thread's batch row
    const int q  = t & 15;         // 0..15

    // Stage-2 accumulators: out[b0+bb, (q*4+yy)*64 + i0+ii], init with bias.
    float acc[4][TI];
#pragma unroll
    for (int yy = 0; yy < 4; ++yy) {
        const int y = q * 4 + yy;
#pragma unroll
        for (int ii = 0; ii < TI; ++ii)
            acc[yy][ii] = bias[y * 64 + i0 + ii];
    }

    for (int xc = 0; xc < 64; ++xc) {
        // ---- stage X chunk: 32 rows x 64 cols, 512 threads x float4 ----
        __syncthreads();  // previous iteration's Xc/z1c readers done
        {
            const int e  = t * 4;
            const int br = e >> 6;    // 0..31
            const int u  = e & 63;    // multiple of 4
            const float4 v = *(const float4*)(x + (size_t)(b0 + br) * 4096 + xc * 64 + u);
            Xc[br][u + 0] = v.x; Xc[br][u + 1] = v.y;
            Xc[br][u + 2] = v.z; Xc[br][u + 3] = v.w;
        }
        __syncthreads();

        // ---- stage 1: z1c[bb][iaa] for iaa in {q, q+16} ----
        {
            float s0 = 0.f, s1 = 0.f;
            const float* c0p = core0 + (size_t)(xc * 64) * 256 + i0 * 4;
#pragma unroll 8
            for (int u = 0; u < 64; ++u) {
                const float xv = Xc[bb][u];
                s0 += xv * c0p[u * 256 + q];
                s1 += xv * c0p[u * 256 + q + 16];
            }
            z1c[bb][q]      = s0;
            z1c[bb][q + 16] = s1;
        }
        __syncthreads();

        // ---- stage 2: acc[yy][ii] += sum_a z1c[bb][ii*4+a] * core1[...] ----
        {
            const float* c1p = core1 + (size_t)(xc * 64) * 256 + i0 * 4;
#pragma unroll
            for (int ii = 0; ii < TI; ++ii) {
                const float z0 = z1c[bb][ii * 4 + 0];
                const float z1 = z1c[bb][ii * 4 + 1];
                const float z2 = z1c[bb][ii * 4 + 2];
                const float z3 = z1c[bb][ii * 4 + 3];
#pragma unroll
                for (int yy = 0; yy < 4; ++yy) {
                    const int y = q * 4 + yy;
                    const float4 c = *(const float4*)(c1p + (size_t)y * 256 + ii * 4);
                    acc[yy][ii] += z0 * c.x + z1 * c.y + z2 * c.z + z3 * c.w;
                }
            }
        }
    }

    // ---- epilogue: write out tile, float4 stores (i0 is 16B-aligned) ----
#pragma unroll
    for (int yy = 0; yy < 4; ++yy) {
        const int y = q * 4 + yy;
        float* dst = out + (size_t)(b0 + bb) * 4096 + y * 64 + i0;
        *(float4*)(dst + 0) = make_float4(acc[yy][0], acc[yy][1], acc[yy][2], acc[yy][3]);
        *(float4*)(dst + 4) = make_float4(acc[yy][4], acc[yy][5], acc[yy][6], acc[yy][7]);
    }
}

extern "C" void kernel_launch(void* const* d_in, const int* in_sizes, int n_in,
                              void* d_out, int out_size, void* d_ws, size_t ws_size,
                              hipStream_t stream) {
    const float* x     = (const float*)d_in[0];
    const float* core0 = (const float*)d_in[1];
    const float* core1 = (const float*)d_in[2];
    const float* bias  = (const float*)d_in[3];
    float* out = (float*)d_out;

    dim3 grid(8192 / TB, 64 / TI);  // (256, 8)
    btt_fused<<<grid, NTHREADS, 0, stream>>>(x, core0, core1, bias, out);
}

// Round 4
// 467.814 us; speedup vs baseline: 10.2933x; 10.2933x over previous
//
#include <hip/hip_runtime.h>

// BTT fused MFMA kernel (round 4): round-3 algorithm (first-launch-verified),
// hardened against LDS phase hazards:
//   - all four LDS regions DISJOINT (no union reuse across phases)
//   - strict write -> barrier -> read -> barrier phase structure
//   - no type-punning through local arrays
//
// out[b, y*64+i] = bias[y*64+i]
//   + sum_{x,a} ( sum_u X[b,x*64+u] * core0[(x*64+u)*256 + i*4+a] )
//               * core1[(x*64+y)*256 + i*4 + a]
//
// MFMA 16x16x32 bf16 layouts (HW-verified):
//   A[m][k]: m=lane&15, k=(lane>>4)*8+j ; B[k][n]: n=lane&15, k=(lane>>4)*8+j
//   D[m][n]: n=lane&15, m=(lane>>4)*4+reg

typedef unsigned short ushort_t;
typedef __attribute__((ext_vector_type(8))) short sfrag8;   // 8 bf16
typedef __attribute__((ext_vector_type(4))) float f32x4;

__device__ inline ushort_t f2bf(float f) {
    unsigned int u = __builtin_bit_cast(unsigned int, f);
    u += 0x7fffu + ((u >> 16) & 1u);   // RNE
    return (ushort_t)(u >> 16);
}

// LDS regions — disjoint, 16B-aligned bases:
#define Z1_OFF    0       // [b]*528 + [ii]*64 + [k]*2   : 33792 B
#define XB_OFF    33792   // [b]*144 + [u]*2             : 9216 B
#define C0_OFF    43008   // [col]*144 + [u]*2           : 4608 B
#define C1_OFF    47616   // [y]*272 + [ii2]*64 + [k]*2  : 17408 B
#define LDS_BYTES 65024

__global__ __launch_bounds__(512, 4) void btt_mfma(
    const float* __restrict__ x,      // (8192, 4096)
    const float* __restrict__ core0,  // (64*64, 256) : [(x,u)][(i,a)]
    const float* __restrict__ core1,  // (64*64, 256) : [(x,y)][(i,a)]
    const float* __restrict__ bias,   // (4096)
    float* __restrict__ out)          // (8192, 4096)
{
    __shared__ char smem[LDS_BYTES];

    const int t    = threadIdx.x;
    const int w    = t >> 6;
    const int lane = t & 63;
    const int quad = lane >> 4;
    const int l16  = lane & 15;

    const int b0 = blockIdx.x * 64;
    const int i0 = blockIdx.y * 8;

    const int mb = w >> 1;   // wave b-tile (both stages)
    const int nt = w & 1;    // stage1 col-tile
    const int yh = w & 1;    // stage2 y-half

    // acc[ia][yt2]: tile (b = mb*16 + quad*4 + reg, y = (yh*2+yt2)*16 + l16, i0+ia)
    f32x4 acc[8][2];
#pragma unroll
    for (int yt2 = 0; yt2 < 2; ++yt2) {
        const int y = (yh * 2 + yt2) * 16 + l16;
#pragma unroll
        for (int ia = 0; ia < 8; ++ia) {
            const float bv = bias[y * 64 + i0 + ia];
            acc[ia][yt2] = (f32x4){bv, bv, bv, bv};
        }
    }

    for (int g = 0; g < 8; ++g) {
        // ============ stage 1: 8 chunks -> Z1L (k = c*4 + a) ============
        for (int c = 0; c < 8; ++c) {
            const int xch = g * 8 + c;
            {   // X chunk 64b x 64u -> bf16 Xbuf
                const int br = t >> 3, u0 = (t & 7) * 8;
                const float* src = x + (size_t)(b0 + br) * 4096 + xch * 64 + u0;
                const float4 v0 = *(const float4*)src;
                const float4 v1 = *(const float4*)(src + 4);
                sfrag8 pk;
                pk[0] = (short)f2bf(v0.x); pk[1] = (short)f2bf(v0.y);
                pk[2] = (short)f2bf(v0.z); pk[3] = (short)f2bf(v0.w);
                pk[4] = (short)f2bf(v1.x); pk[5] = (short)f2bf(v1.y);
                pk[6] = (short)f2bf(v1.z); pk[7] = (short)f2bf(v1.w);
                *(sfrag8*)(smem + XB_OFF + br * 144 + u0 * 2) = pk;
            }
            {   // C0 slice 64u x 32col -> transposed C0T[col][u]
                const int u = t >> 3, c4 = (t & 7) * 4;
                const float4 v = *(const float4*)(core0 + (size_t)(xch * 64 + u) * 256 + i0 * 4 + c4);
                ushort_t* dst = (ushort_t*)(smem + C0_OFF + u * 2);
                dst[(c4 + 0) * 72] = f2bf(v.x);
                dst[(c4 + 1) * 72] = f2bf(v.y);
                dst[(c4 + 2) * 72] = f2bf(v.z);
                dst[(c4 + 3) * 72] = f2bf(v.w);
            }
            __syncthreads();   // staging visible to all waves
            {   // one 16x16 z1 tile per wave, K=64
                const char* arow = smem + XB_OFF + (mb * 16 + l16) * 144 + quad * 16;
                const char* brow = smem + C0_OFF + (nt * 16 + l16) * 144 + quad * 16;
                const sfrag8 a0  = *(const sfrag8*)(arow);
                const sfrag8 a1  = *(const sfrag8*)(arow + 64);
                const sfrag8 bb0 = *(const sfrag8*)(brow);
                const sfrag8 bb1 = *(const sfrag8*)(brow + 64);
                f32x4 d = {0.f, 0.f, 0.f, 0.f};
                d = __builtin_amdgcn_mfma_f32_16x16x32_bf16(a0, bb0, d, 0, 0, 0);
                d = __builtin_amdgcn_mfma_f32_16x16x32_bf16(a1, bb1, d, 0, 0, 0);
                const int col = nt * 16 + l16;     // (ii, a)
                const int ii = col >> 2, a = col & 3;
                char* zd = smem + Z1_OFF + (mb * 16 + quad * 4) * 528 + ii * 64 + (c * 4 + a) * 2;
                *(ushort_t*)(zd)           = f2bf(d[0]);
                *(ushort_t*)(zd + 528)     = f2bf(d[1]);
                *(ushort_t*)(zd + 2 * 528) = f2bf(d[2]);
                *(ushort_t*)(zd + 3 * 528) = f2bf(d[3]);
            }
            __syncthreads();   // z1 writes visible; staging readers done
        }
        // ============ stage 2: contract group (K=32) into acc ============
        for (int ig = 0; ig < 2; ++ig) {
            {   // C1T staging: [y][ii2][k = xg*4+a]
                const int ii2 = t & 3, yy = (t >> 2) & 63, xh = t >> 8;
                const float* src = core1 + (size_t)yy * 256 + (i0 + ig * 4 + ii2) * 4
                                 + (size_t)(g * 8) * 16384;
#pragma unroll
                for (int p = 0; p < 4; ++p) {
                    const int xg = p * 2 + xh;
                    const float4 v = *(const float4*)(src + (size_t)xg * 16384);
                    ushort4 pk = make_ushort4(f2bf(v.x), f2bf(v.y), f2bf(v.z), f2bf(v.w));
                    *(ushort4*)(smem + C1_OFF + yy * 272 + ii2 * 64 + xg * 8) = pk;
                }
            }
            __syncthreads();   // C1T visible
            {   // per wave: 4 i x 2 y-tiles
#pragma unroll
                for (int ii2 = 0; ii2 < 4; ++ii2) {
                    const sfrag8 af = *(const sfrag8*)(smem + Z1_OFF + (mb * 16 + l16) * 528
                                                       + (ig * 4 + ii2) * 64 + quad * 16);
#pragma unroll
                    for (int yt2 = 0; yt2 < 2; ++yt2) {
                        const int y16 = (yh * 2 + yt2) * 16 + l16;
                        const sfrag8 bf = *(const sfrag8*)(smem + C1_OFF + y16 * 272 + ii2 * 64 + quad * 16);
                        acc[ig * 4 + ii2][yt2] =
                            __builtin_amdgcn_mfma_f32_16x16x32_bf16(af, bf, acc[ig * 4 + ii2][yt2], 0, 0, 0);
                    }
                }
            }
            __syncthreads();   // C1T/Z1L readers done before next writes
        }
    }

    // ============ epilogue ============
#pragma unroll
    for (int yt2 = 0; yt2 < 2; ++yt2) {
        const int y = (yh * 2 + yt2) * 16 + l16;
#pragma unroll
        for (int reg = 0; reg < 4; ++reg) {
            const int b = mb * 16 + quad * 4 + reg;
            float* dst = out + (size_t)(b0 + b) * 4096 + y * 64 + i0;
            *(float4*)dst       = make_float4(acc[0][yt2][reg], acc[1][yt2][reg],
                                              acc[2][yt2][reg], acc[3][yt2][reg]);
            *(float4*)(dst + 4) = make_float4(acc[4][yt2][reg], acc[5][yt2][reg],
                                              acc[6][yt2][reg], acc[7][yt2][reg]);
        }
    }
}

extern "C" void kernel_launch(void* const* d_in, const int* in_sizes, int n_in,
                              void* d_out, int out_size, void* d_ws, size_t ws_size,
                              hipStream_t stream) {
    const float* x     = (const float*)d_in[0];
    const float* core0 = (const float*)d_in[1];
    const float* core1 = (const float*)d_in[2];
    const float* bias  = (const float*)d_in[3];
    float* out = (float*)d_out;

    dim3 grid(8192 / 64, 64 / 8);   // (128, 8)
    btt_mfma<<<grid, 512, 0, stream>>>(x, core0, core1, bias, out);
}